// Round 7
// baseline (84.812 us; speedup 1.0000x reference)
//
#include <hip/hip_runtime.h>
#include <math.h>

#define D_DIM 128
#define K_DIM 64
#define R_DIM 8
#define B_DIM 8192
#define KG    4          // k-groups (16 k each)
#define ESTR  161        // floats per epilogue row
#define TCH   5120       // bf16 per T chunk: 160 cols x 32 k

// ws layout:
//   T   : bf16 [KG][8 chunks][160 cols][32 k] = 163840 ushort = 81920 floats
//   c0  : float [K]        at float offset 81920
//   part: float [B][KG][2] at float offset 81984  (65536 floats)
//   Xg  : bf16 [256 rt][32 row][32 granule][8]  at float offset 147520
#define WS_C0F   81920
#define WS_PARTF 81984
#define WS_XGF   147520

typedef __bf16 bf16x8 __attribute__((ext_vector_type(8)));
typedef float  f32x4  __attribute__((ext_vector_type(4)));

static __device__ inline unsigned short f2bf(float f) {
  union { float f; unsigned int u; } v; v.f = f;
  unsigned int u = v.u;
  unsigned int lsb = (u >> 16) & 1;
  u += 0x7fffu + lsb;                 // round-to-nearest-even
  return (unsigned short)(u >> 16);
}

// ---------------------------------------------------------------------------
// Per-k precompute (r3 math, r6 layout). Grid = K blocks, 128 threads (=D).
// T layout [kg][chunk][col][32k]: chunks 0..3 = y-part (K 0..127),
// 4..7 = y^2-part; per k 10 cols: 0..7 = W/sqrt2 (y-part; 0 in y^2-part),
// col 8 = h' (y) / -0.5*s_inv (y^2), col 9 pad.
// ---------------------------------------------------------------------------
__global__ __launch_bounds__(128) void precomp_kernel(
    const float* __restrict__ m, const float* __restrict__ delta,
    const float* __restrict__ U, const float* __restrict__ lar,
    float* __restrict__ ws) {
  const int k = blockIdx.x;
  const int d = threadIdx.x;  // 0..127

  __shared__ float U_l[D_DIM][R_DIM];
  __shared__ float V_l[D_DIM][R_DIM];
  __shared__ float W_l[D_DIM][R_DIM];
  __shared__ float m_l[D_DIM];
  __shared__ float red[64];
  __shared__ float Linv_s[R_DIM][R_DIM];
  __shared__ float q_s[R_DIM];
  __shared__ float c0_s[1];
  __shared__ float redA[D_DIM], redB[D_DIM], redC[D_DIM];

  const float dl    = delta[k * D_DIM + d];
  const float s_inv = expf(-dl);
  const float mv    = m[k * D_DIM + d];
  m_l[d] = mv;
  const float* Up = U + (size_t)(k * D_DIM + d) * R_DIM;
#pragma unroll
  for (int r = 0; r < R_DIM; ++r) {
    float u = Up[r];
    U_l[d][r] = u;
    V_l[d][r] = u * s_inv;
  }
  redA[d] = dl;
  redB[d] = mv * mv * s_inv;
  redC[d] = (d < K_DIM) ? lar[d] : 0.f;
  __syncthreads();

  if (d < 64) {
    const int r = d >> 3, s = d & 7;
    float acc = (r == s) ? 1.0f : 0.0f;
#pragma unroll 8
    for (int dd = 0; dd < D_DIM; ++dd) acc += U_l[dd][r] * V_l[dd][s];
    red[d] = acc;
  }
  __syncthreads();

  for (int off = 64; off > 0; off >>= 1) {
    if (d < off) {
      redA[d] += redA[d + off];
      redB[d] += redB[d + off];
      redC[d] += redC[d + off];
    }
    __syncthreads();
  }

  if (d == 0) {
    float Lm[8][8];
#pragma unroll
    for (int i = 0; i < 8; ++i) {
#pragma unroll
      for (int j = 0; j < 8; ++j) {
        if (j > i) continue;
        float sum = red[i * 8 + j];
#pragma unroll
        for (int p = 0; p < 8; ++p)
          if (p < j) sum -= Lm[i][p] * Lm[j][p];
        if (i == j) Lm[i][i] = sqrtf(sum);
        else        Lm[i][j] = sum / Lm[j][j];
      }
    }
    float ld = 0.f;
#pragma unroll
    for (int i = 0; i < 8; ++i) ld += logf(Lm[i][i]);

    float Li[8][8];
#pragma unroll
    for (int i = 0; i < 8; ++i)
#pragma unroll
      for (int j = 0; j < 8; ++j) Li[i][j] = 0.f;
#pragma unroll
    for (int j = 0; j < 8; ++j) {
      Li[j][j] = 1.0f / Lm[j][j];
#pragma unroll
      for (int i = 0; i < 8; ++i) {
        if (i <= j) continue;
        float sum = 0.f;
#pragma unroll
        for (int p = 0; p < 8; ++p)
          if (p >= j && p < i) sum += Lm[i][p] * Li[p][j];
        Li[i][j] = -sum / Lm[i][i];
      }
    }
#pragma unroll
    for (int i = 0; i < 8; ++i)
#pragma unroll
      for (int j = 0; j < 8; ++j) Linv_s[i][j] = Li[i][j];

    const float mean = redC[0] * (1.0f / K_DIM);
    const float log_alpha = lar[k] - mean;       // /eps, eps=1
    const float logdetS = redA[0] + 2.0f * ld;
    const float LOG2PI = 1.8378770664093453f;
    const float log_norm = 0.5f * ((float)D_DIM * LOG2PI + logdetS);
    c0_s[0] = log_alpha - log_norm - 0.5f * redB[0];
  }
  __syncthreads();

  float Wr[R_DIM];
#pragma unroll
  for (int r = 0; r < R_DIM; ++r) {
    float acc = 0.f;
#pragma unroll
    for (int s2 = 0; s2 < R_DIM; ++s2)
      if (s2 <= r) acc += V_l[d][s2] * Linv_s[r][s2];
    Wr[r] = acc;
    W_l[d][r] = acc;
  }
  __syncthreads();

  if (d < R_DIM) {
    float acc = 0.f;
#pragma unroll 8
    for (int dd = 0; dd < D_DIM; ++dd) acc += W_l[dd][d] * m_l[dd];
    q_s[d] = acc;
  }
  __syncthreads();

  float hp = mv * s_inv;
#pragma unroll
  for (int r = 0; r < R_DIM; ++r) hp -= q_s[r] * Wr[r];

  const float INV_SQRT2 = 0.70710678118654752f;
  unsigned short* T = (unsigned short*)ws;
  const int kg = k >> 4, kl = k & 15;
  const int chunk = d >> 5, pos = d & 31;
  const size_t base_y = (((size_t)kg * 8 + chunk) * 160) * 32;
  const size_t base_q = (((size_t)kg * 8 + 4 + chunk) * 160) * 32;
#pragma unroll
  for (int c = 0; c < 8; ++c) {
    T[base_y + (size_t)(kl * 10 + c) * 32 + pos] = f2bf(Wr[c] * INV_SQRT2);
    T[base_q + (size_t)(kl * 10 + c) * 32 + pos] = 0;
  }
  T[base_y + (size_t)(kl * 10 + 8) * 32 + pos] = f2bf(hp);
  T[base_q + (size_t)(kl * 10 + 8) * 32 + pos] = f2bf(-0.5f * s_inv);
  T[base_y + (size_t)(kl * 10 + 9) * 32 + pos] = 0;
  T[base_q + (size_t)(kl * 10 + 9) * 32 + pos] = 0;

  if (d == 0) {
    float qq = 0.f;
#pragma unroll
    for (int r = 0; r < R_DIM; ++r) qq += q_s[r] * q_s[r];
    ws[WS_C0F + k] = c0_s[0] + 0.5f * qq;   // c0' = c0 + 0.5*||q||^2
  }
}

// ---------------------------------------------------------------------------
// X prep: X[row] = [bf16(y[row]) (granules 0..15) | bf16(y[row]^2) (16..31)],
// stored pre-swizzled: Xg[row*32 + (seg ^ (row&31))] = granule(row, seg).
// The XOR bakes the LDS bank swizzle into global layout so logz can stage
// with straight contiguous global_load_lds. Grid = 1024 x 256 (1 granule/thr).
// ---------------------------------------------------------------------------
__global__ __launch_bounds__(256) void x_prep_kernel(
    const float* __restrict__ y, float* __restrict__ ws) {
  const int i   = blockIdx.x * 256 + threadIdx.x;   // 0..262143
  const int row = i >> 5;
  const int seg = i & 31;
  const float4* ya = (const float4*)y + (size_t)row * 32 + (seg & 15) * 2;
  float4 a = ya[0], b = ya[1];
  if (seg >= 16) {
    a.x *= a.x; a.y *= a.y; a.z *= a.z; a.w *= a.w;
    b.x *= b.x; b.y *= b.y; b.z *= b.z; b.w *= b.w;
  }
  union { unsigned short us[8]; uint4 v; } o;
  o.us[0] = f2bf(a.x); o.us[1] = f2bf(a.y); o.us[2] = f2bf(a.z); o.us[3] = f2bf(a.w);
  o.us[4] = f2bf(b.x); o.us[5] = f2bf(b.y); o.us[6] = f2bf(b.z); o.us[7] = f2bf(b.w);
  uint4* xg = (uint4*)(ws + WS_XGF);
  xg[(size_t)row * 32 + (seg ^ (row & 31))] = o.v;
}

// ---------------------------------------------------------------------------
// MFMA main kernel. Block = 256 thr = 4 waves (2x2 over 32 rows x 160 cols).
// X staged via global_load_lds from pre-swizzled Xg (no VALU, no ds_writes);
// T chunks staged 2-at-a-time via global_load_lds. 8 K-iters of
// mfma_16x16x32_bf16. Grid = 256 rt x 4 kg = 1024 blocks (4/CU).
// ---------------------------------------------------------------------------
__global__ __launch_bounds__(256, 4) void logz_main(
    const float* __restrict__ ws, float* __restrict__ part) {
  __shared__ __align__(16) unsigned short sX[32 * 256];    // 16384 B, swizzled
  __shared__ __align__(16) float sbuf[32 * ESTR];          // 20608 B (T / evals)
  __shared__ float vals2[32 * 17];

  const int tid   = threadIdx.x;            // 0..255
  const int lane  = tid & 63;
  const int wv    = tid >> 6;               // 0..3
  const int wr    = wv >> 1;                // row-wave 0..1
  const int wc    = wv & 1;                 // col-wave 0..1
  const int col_l = lane & 15;
  const int quad  = lane >> 4;
  const int rt    = (int)blockIdx.x >> 2;
  const int kg    = (int)blockIdx.x & 3;

  // ---- stage X tile: 16 KB contiguous, 4 x 1KB per wave ----
  {
    const float* xsrc = ws + WS_XGF + (size_t)rt * 4096;   // 16 KB in floats
#pragma unroll
    for (int j = 0; j < 4; ++j) {
      const int off = (wv * 4 + j) * 256;                  // floats
      __builtin_amdgcn_global_load_lds(
          (const __attribute__((address_space(1))) void*)(xsrc + off + lane * 4),
          (__attribute__((address_space(3))) void*)((float*)sX + off),
          16, 0, 0);
    }
  }

  f32x4 acc[5];
#pragma unroll
  for (int f = 0; f < 5; ++f) { acc[f][0] = 0.f; acc[f][1] = 0.f; acc[f][2] = 0.f; acc[f][3] = 0.f; }

  const float* tG = ws + (size_t)kg * 8 * (TCH / 2);   // float units
  unsigned short* sT = (unsigned short*)sbuf;
  const int rowA = wr * 16 + col_l;                    // A-fragment row (0..31)

  for (int pair = 0; pair < 4; ++pair) {
    if (pair) __syncthreads();   // prev pair's compute done
    // stage chunks 2*pair, 2*pair+1 : 20480 B = 20 x 1KB insts, 5 per wave
    {
      const float* src = tG + (size_t)pair * TCH;      // 2 chunks = 5120 floats
#pragma unroll
      for (int j = 0; j < 5; ++j) {
        const int off = (wv * 5 + j) * 256;            // floats
        __builtin_amdgcn_global_load_lds(
            (const __attribute__((address_space(1))) void*)(src + off + lane * 4),
            (__attribute__((address_space(3))) void*)((float*)sbuf + off),
            16, 0, 0);
      }
    }
    __syncthreads();   // drains vmcnt (covers X on pair 0)
#pragma unroll
    for (int ii = 0; ii < 2; ++ii) {
      const int kiter = pair * 2 + ii;
      // swizzled A-granule: g = row*32 + ((kiter*4+quad) ^ row)
      const bf16x8 a = *(const bf16x8*)(sX + ((size_t)rowA * 32
                          + (((kiter * 4 + quad) ^ rowA) & 31)) * 8);
      const unsigned short* cb = sT + ii * TCH;
#pragma unroll
      for (int f = 0; f < 5; ++f) {
        const bf16x8 b = *(const bf16x8*)(cb + (wc * 80 + f * 16 + col_l) * 32
                                             + quad * 8);
        acc[f] = __builtin_amdgcn_mfma_f32_16x16x32_bf16(a, b, acc[f], 0, 0, 0);
      }
    }
  }

  __syncthreads();   // all MFMA LDS reads done; reuse sbuf as evals
  float* evals = sbuf;
#pragma unroll
  for (int f = 0; f < 5; ++f) {
    const int col = wc * 80 + f * 16 + col_l;
    const int c10 = col % 10;
#pragma unroll
    for (int reg = 0; reg < 4; ++reg) {
      const float v = acc[f][reg];
      evals[(wr * 16 + quad * 4 + reg) * ESTR + col] = (c10 == 8) ? v : v * v;
    }
  }
  __syncthreads();

  const float* c0p = ws + WS_C0F + kg * 16;
#pragma unroll
  for (int j = 0; j < 2; ++j) {
    const int idx = tid + j * 256;
    const int row = idx >> 4, kl = idx & 15;
    const float* e = evals + row * ESTR + kl * 10;
    float s = c0p[kl] + e[8];
#pragma unroll
    for (int c = 0; c < 8; ++c) s += e[c];
    vals2[row * 17 + kl] = s;
  }
  __syncthreads();

  if (tid < 32) {
    const int row = tid;
    float mx = -INFINITY;
#pragma unroll
    for (int j = 0; j < 16; ++j) mx = fmaxf(mx, vals2[row * 17 + j]);
    float s = 0.f;
#pragma unroll
    for (int j = 0; j < 16; ++j) s += expf(vals2[row * 17 + j] - mx);
    *(float2*)(part + ((size_t)(rt * 32 + row) * KG + kg) * 2) = make_float2(mx, s);
  }
}

// ---------------------------------------------------------------------------
// Combine 4 kgroup-partials per b.
// ---------------------------------------------------------------------------
__global__ __launch_bounds__(256) void reduce_kernel(
    const float* __restrict__ part, float* __restrict__ out) {
  const int b = blockIdx.x * 256 + threadIdx.x;
  const float4 a0 = ((const float4*)part)[b * 2];
  const float4 a1 = ((const float4*)part)[b * 2 + 1];
  float mx = fmaxf(fmaxf(a0.x, a0.z), fmaxf(a1.x, a1.z));
  float s = a0.y * expf(a0.x - mx) + a0.w * expf(a0.z - mx)
          + a1.y * expf(a1.x - mx) + a1.w * expf(a1.z - mx);
  out[b] = mx + logf(s);
}

extern "C" void kernel_launch(void* const* d_in, const int* in_sizes, int n_in,
                              void* d_out, int out_size, void* d_ws, size_t ws_size,
                              hipStream_t stream) {
  const float* y     = (const float*)d_in[0];
  const float* m     = (const float*)d_in[1];
  const float* delta = (const float*)d_in[2];
  const float* U     = (const float*)d_in[3];
  const float* lar   = (const float*)d_in[4];
  float* out = (float*)d_out;
  float* ws  = (float*)d_ws;

  precomp_kernel<<<K_DIM, 128, 0, stream>>>(m, delta, U, lar, ws);
  x_prep_kernel<<<B_DIM * 32 / 256, 256, 0, stream>>>(y, ws);
  logz_main<<<(B_DIM / 32) * KG, 256, 0, stream>>>(ws, ws + WS_PARTF);
  reduce_kernel<<<B_DIM / 256, 256, 0, stream>>>(ws + WS_PARTF, out);
}

// Round 8
// 80.375 us; speedup vs baseline: 1.0552x; 1.0552x over previous
//
#include <hip/hip_runtime.h>
#include <math.h>

#define D_DIM 128
#define K_DIM 64
#define R_DIM 8
#define B_DIM 8192
#define XSTR  264        // ushort per staged X row (256 data + 8 pad)

// ws layout (float offsets):
//   T  : bf16 [4 kg][8 chunk][160 col][32 k] = 163840 ushort = 81920 floats
//   c0 : float [K] at 81920
#define WS_C0F   81920

typedef __bf16 bf16x8 __attribute__((ext_vector_type(8)));
typedef float  f32x4  __attribute__((ext_vector_type(4)));

static __device__ inline unsigned short f2bf(float f) {
  union { float f; unsigned int u; } v; v.f = f;
  unsigned int u = v.u;
  unsigned int lsb = (u >> 16) & 1;
  u += 0x7fffu + lsb;                 // round-to-nearest-even
  return (unsigned short)(u >> 16);
}

// ---------------------------------------------------------------------------
// Per-k precompute (r6-proven). Grid = K blocks, 128 threads (=D).
// T layout [kg][chunk][col][32k]: chunks 0..3 = y-part, 4..7 = y^2-part;
// per k 10 cols: 0..7 = W/sqrt2 (y; 0 in y^2), col 8 = h' (y) /
// -0.5*s_inv (y^2), col 9 pad.
// ---------------------------------------------------------------------------
__global__ __launch_bounds__(128) void precomp_kernel(
    const float* __restrict__ m, const float* __restrict__ delta,
    const float* __restrict__ U, const float* __restrict__ lar,
    float* __restrict__ ws) {
  const int k = blockIdx.x;
  const int d = threadIdx.x;  // 0..127

  __shared__ float U_l[D_DIM][R_DIM];
  __shared__ float V_l[D_DIM][R_DIM];
  __shared__ float W_l[D_DIM][R_DIM];
  __shared__ float m_l[D_DIM];
  __shared__ float red[64];
  __shared__ float Linv_s[R_DIM][R_DIM];
  __shared__ float q_s[R_DIM];
  __shared__ float c0_s[1];
  __shared__ float redA[D_DIM], redB[D_DIM], redC[D_DIM];

  const float dl    = delta[k * D_DIM + d];
  const float s_inv = expf(-dl);
  const float mv    = m[k * D_DIM + d];
  m_l[d] = mv;
  const float* Up = U + (size_t)(k * D_DIM + d) * R_DIM;
#pragma unroll
  for (int r = 0; r < R_DIM; ++r) {
    float u = Up[r];
    U_l[d][r] = u;
    V_l[d][r] = u * s_inv;
  }
  redA[d] = dl;
  redB[d] = mv * mv * s_inv;
  redC[d] = (d < K_DIM) ? lar[d] : 0.f;
  __syncthreads();

  if (d < 64) {
    const int r = d >> 3, s = d & 7;
    float acc = (r == s) ? 1.0f : 0.0f;
#pragma unroll 8
    for (int dd = 0; dd < D_DIM; ++dd) acc += U_l[dd][r] * V_l[dd][s];
    red[d] = acc;
  }
  __syncthreads();

  for (int off = 64; off > 0; off >>= 1) {
    if (d < off) {
      redA[d] += redA[d + off];
      redB[d] += redB[d + off];
      redC[d] += redC[d + off];
    }
    __syncthreads();
  }

  if (d == 0) {
    float Lm[8][8];
#pragma unroll
    for (int i = 0; i < 8; ++i) {
#pragma unroll
      for (int j = 0; j < 8; ++j) {
        if (j > i) continue;
        float sum = red[i * 8 + j];
#pragma unroll
        for (int p = 0; p < 8; ++p)
          if (p < j) sum -= Lm[i][p] * Lm[j][p];
        if (i == j) Lm[i][i] = sqrtf(sum);
        else        Lm[i][j] = sum / Lm[j][j];
      }
    }
    float ld = 0.f;
#pragma unroll
    for (int i = 0; i < 8; ++i) ld += logf(Lm[i][i]);

    float Li[8][8];
#pragma unroll
    for (int i = 0; i < 8; ++i)
#pragma unroll
      for (int j = 0; j < 8; ++j) Li[i][j] = 0.f;
#pragma unroll
    for (int j = 0; j < 8; ++j) {
      Li[j][j] = 1.0f / Lm[j][j];
#pragma unroll
      for (int i = 0; i < 8; ++i) {
        if (i <= j) continue;
        float sum = 0.f;
#pragma unroll
        for (int p = 0; p < 8; ++p)
          if (p >= j && p < i) sum += Lm[i][p] * Li[p][j];
        Li[i][j] = -sum / Lm[i][i];
      }
    }
#pragma unroll
    for (int i = 0; i < 8; ++i)
#pragma unroll
      for (int j = 0; j < 8; ++j) Linv_s[i][j] = Li[i][j];

    const float mean = redC[0] * (1.0f / K_DIM);
    const float log_alpha = lar[k] - mean;       // /eps, eps=1
    const float logdetS = redA[0] + 2.0f * ld;
    const float LOG2PI = 1.8378770664093453f;
    const float log_norm = 0.5f * ((float)D_DIM * LOG2PI + logdetS);
    c0_s[0] = log_alpha - log_norm - 0.5f * redB[0];
  }
  __syncthreads();

  float Wr[R_DIM];
#pragma unroll
  for (int r = 0; r < R_DIM; ++r) {
    float acc = 0.f;
#pragma unroll
    for (int s2 = 0; s2 < R_DIM; ++s2)
      if (s2 <= r) acc += V_l[d][s2] * Linv_s[r][s2];
    Wr[r] = acc;
    W_l[d][r] = acc;
  }
  __syncthreads();

  if (d < R_DIM) {
    float acc = 0.f;
#pragma unroll 8
    for (int dd = 0; dd < D_DIM; ++dd) acc += W_l[dd][d] * m_l[dd];
    q_s[d] = acc;
  }
  __syncthreads();

  float hp = mv * s_inv;
#pragma unroll
  for (int r = 0; r < R_DIM; ++r) hp -= q_s[r] * Wr[r];

  const float INV_SQRT2 = 0.70710678118654752f;
  unsigned short* T = (unsigned short*)ws;
  const int kg = k >> 4, kl = k & 15;
  const int chunk = d >> 5, pos = d & 31;
  const size_t base_y = (((size_t)kg * 8 + chunk) * 160) * 32;
  const size_t base_q = (((size_t)kg * 8 + 4 + chunk) * 160) * 32;
#pragma unroll
  for (int c = 0; c < 8; ++c) {
    T[base_y + (size_t)(kl * 10 + c) * 32 + pos] = f2bf(Wr[c] * INV_SQRT2);
    T[base_q + (size_t)(kl * 10 + c) * 32 + pos] = 0;
  }
  T[base_y + (size_t)(kl * 10 + 8) * 32 + pos] = f2bf(hp);
  T[base_q + (size_t)(kl * 10 + 8) * 32 + pos] = f2bf(-0.5f * s_inv);
  T[base_y + (size_t)(kl * 10 + 9) * 32 + pos] = 0;
  T[base_q + (size_t)(kl * 10 + 9) * 32 + pos] = 0;

  if (d == 0) {
    float qq = 0.f;
#pragma unroll
    for (int r = 0; r < R_DIM; ++r) qq += q_s[r] * q_s[r];
    ws[WS_C0F + k] = c0_s[0] + 0.5f * qq;   // c0' = c0 + 0.5*||q||^2
  }
}

// ---------------------------------------------------------------------------
// Fused MFMA kernel: block = 512 thr = 8 waves = 32 rows x ALL 64 k.
// Waves: wr (2 row-waves) x wc (4 col-waves, wc = kg). T double-buffered
// 2 x 40KB via global_load_lds (stage c+1 overlaps compute c); X converted
// in-block once. Full 64-k logsumexp in-block -> out directly.
// Grid = 256 blocks (1/CU, 105 KB LDS).
// ---------------------------------------------------------------------------
__global__ __launch_bounds__(512, 1) void logz_full(
    const float* __restrict__ y, const float* __restrict__ ws,
    float* __restrict__ out) {
  __shared__ __align__(16) char smem[16896 + 81920];  // sX | sT[2]; evals overlay
  __shared__ float vals2[32 * 65];                     // [row][k], stride 65

  unsigned short* sX = (unsigned short*)smem;               // 32 x XSTR
  unsigned short* sT = (unsigned short*)(smem + 16896);     // [2][4][160][32]

  const int tid   = threadIdx.x;            // 0..511
  const int lane  = tid & 63;
  const int wv    = tid >> 6;               // 0..7
  const int wr    = wv & 1;                 // row-wave
  const int wc    = wv >> 1;                // col-wave = kg
  const int col_l = lane & 15;
  const int quad  = lane >> 4;
  const int r0    = (int)blockIdx.x * 32;

  // staging assignment for T chunks: inst m = wv*5 + j (40 x 1KB per chunk)
  const int kg_m = wv >> 1;                 // source kg for this wave's insts
  const int wi5  = (wv & 1) * 5;

  // ---- issue T chunk 0 into buf 0 (async) ----
  {
#pragma unroll
    for (int j = 0; j < 5; ++j) {
      const int within = wi5 + j;           // 0..9
      const float* src = ws + (size_t)kg_m * 20480 + 0 * 2560 + within * 256;
      __builtin_amdgcn_global_load_lds(
          (const __attribute__((address_space(1))) void*)(src + lane * 4),
          (__attribute__((address_space(3))) void*)(sT + kg_m * 5120 + within * 512),
          16, 0, 0);
    }
  }

  // ---- convert X = [bf16(y), bf16(y^2)] into sX (overlaps T staging) ----
  {
#pragma unroll
    for (int j = 0; j < 2; ++j) {
      const int idx = tid + j * 512;        // granule 0..1023
      const int row = idx >> 5, g = idx & 31;
      const float4* ya = (const float4*)y + (size_t)(r0 + row) * 32 + (g & 15) * 2;
      float4 a = ya[0], b = ya[1];
      if (g >= 16) {
        a.x *= a.x; a.y *= a.y; a.z *= a.z; a.w *= a.w;
        b.x *= b.x; b.y *= b.y; b.z *= b.z; b.w *= b.w;
      }
      union { unsigned short us[8]; uint4 v; } o;
      o.us[0] = f2bf(a.x); o.us[1] = f2bf(a.y); o.us[2] = f2bf(a.z); o.us[3] = f2bf(a.w);
      o.us[4] = f2bf(b.x); o.us[5] = f2bf(b.y); o.us[6] = f2bf(b.z); o.us[7] = f2bf(b.w);
      *(uint4*)(sX + row * XSTR + g * 8) = o.v;
    }
  }

  f32x4 acc[10];
#pragma unroll
  for (int f = 0; f < 10; ++f) { acc[f][0] = 0.f; acc[f][1] = 0.f; acc[f][2] = 0.f; acc[f][3] = 0.f; }

  const int rowA = wr * 16 + col_l;         // A-fragment row (0..31)

  for (int c = 0; c < 8; ++c) {
    __syncthreads();   // drains vmcnt: chunk c staged; prev compute done
    if (c < 7) {
      const int nb = (c + 1) & 1;
#pragma unroll
      for (int j = 0; j < 5; ++j) {
        const int within = wi5 + j;
        const float* src = ws + (size_t)kg_m * 20480 + (c + 1) * 2560 + within * 256;
        __builtin_amdgcn_global_load_lds(
            (const __attribute__((address_space(1))) void*)(src + lane * 4),
            (__attribute__((address_space(3))) void*)(sT + nb * 20480 + kg_m * 5120 + within * 512),
            16, 0, 0);
      }
    }
    // compute chunk c from buf c&1
    const bf16x8 a = *(const bf16x8*)(sX + rowA * XSTR + c * 32 + quad * 8);
    const unsigned short* tb = sT + (c & 1) * 20480 + wc * 5120;
#pragma unroll
    for (int f = 0; f < 10; ++f) {
      const bf16x8 b = *(const bf16x8*)(tb + (f * 16 + col_l) * 32 + quad * 8);
      acc[f] = __builtin_amdgcn_mfma_f32_16x16x32_bf16(a, b, acc[f], 0, 0, 0);
    }
  }

  __syncthreads();   // all MFMA LDS reads done; overlay evals on smem
  float* evals = (float*)smem;              // [32][640]
#pragma unroll
  for (int f = 0; f < 10; ++f) {
    const int c_in = f * 16 + col_l;        // 0..159 within kg
    const int c10  = c_in % 10;
    const int col  = wc * 160 + c_in;
#pragma unroll
    for (int reg = 0; reg < 4; ++reg) {
      const int row = wr * 16 + quad * 4 + reg;
      const float v = acc[f][reg];
      evals[row * 640 + col] = (c10 == 8) ? v : v * v;
    }
  }
  __syncthreads();

  // assemble vals2[row][k] = c0'[k] + e[8] + sum_{c<8} e[c]
  const float* c0p = ws + WS_C0F;
#pragma unroll
  for (int j = 0; j < 4; ++j) {
    const int idx = tid + j * 512;
    const int row = idx >> 6, kl = idx & 63;
    const float* e = evals + row * 640 + kl * 10;
    float s = c0p[kl] + e[8];
#pragma unroll
    for (int c = 0; c < 8; ++c) s += e[c];
    vals2[row * 65 + kl] = s;
  }
  __syncthreads();

  // per-row 64-k logsumexp: 4 rows per wave, lane = k, butterfly
#pragma unroll
  for (int rr = 0; rr < 4; ++rr) {
    const int row = wv * 4 + rr;
    const float val = vals2[row * 65 + lane];
    float mx = val;
#pragma unroll
    for (int off = 1; off < 64; off <<= 1)
      mx = fmaxf(mx, __shfl_xor(mx, off, 64));
    float ex = expf(val - mx);
#pragma unroll
    for (int off = 1; off < 64; off <<= 1)
      ex += __shfl_xor(ex, off, 64);
    if (lane == 0) out[r0 + row] = mx + logf(ex);
  }
}

extern "C" void kernel_launch(void* const* d_in, const int* in_sizes, int n_in,
                              void* d_out, int out_size, void* d_ws, size_t ws_size,
                              hipStream_t stream) {
  const float* y     = (const float*)d_in[0];
  const float* m     = (const float*)d_in[1];
  const float* delta = (const float*)d_in[2];
  const float* U     = (const float*)d_in[3];
  const float* lar   = (const float*)d_in[4];
  float* out = (float*)d_out;
  float* ws  = (float*)d_ws;

  precomp_kernel<<<K_DIM, 128, 0, stream>>>(m, delta, U, lar, ws);
  logz_full<<<B_DIM / 32, 512, 0, stream>>>(y, ws, out);
}

// Round 9
// 80.315 us; speedup vs baseline: 1.0560x; 1.0007x over previous
//
#include <hip/hip_runtime.h>
#include <math.h>

#define D_DIM 128
#define K_DIM 64
#define R_DIM 8
#define B_DIM 8192
#define XSTR  264        // ushort per staged X row (256 data + 8 pad)

// ws layout (float offsets):
//   T  : bf16 [4 kg][8 chunk][9 cc][16 kl][32 k] = 147456 ushort = 73728 floats
//   c0 : float [K] at 73728
#define WS_C0F   73728

typedef __bf16 bf16x8 __attribute__((ext_vector_type(8)));
typedef float  f32x4  __attribute__((ext_vector_type(4)));

static __device__ inline unsigned short f2bf(float f) {
  union { float f; unsigned int u; } v; v.f = f;
  unsigned int u = v.u;
  unsigned int lsb = (u >> 16) & 1;
  u += 0x7fffu + lsb;                 // round-to-nearest-even
  return (unsigned short)(u >> 16);
}

// ---------------------------------------------------------------------------
// Per-k precompute. Grid = K blocks, 128 threads (=D).
// T layout [kg][chunk][cc][kl][32k]: chunks 0..3 = y-part, 4..7 = y^2-part;
// cc 0..7 = W/sqrt2 (y-part; 0 in y^2-part), cc 8 = h' (y) / -0.5*s_inv (y^2).
// Column-major-in-cc so each MFMA B-lane (n=col_l=kl) owns one k across all
// cc fragments -> per-k sums stay in registers in the main kernel.
// ---------------------------------------------------------------------------
__global__ __launch_bounds__(128) void precomp_kernel(
    const float* __restrict__ m, const float* __restrict__ delta,
    const float* __restrict__ U, const float* __restrict__ lar,
    float* __restrict__ ws) {
  const int k = blockIdx.x;
  const int d = threadIdx.x;  // 0..127

  __shared__ float U_l[D_DIM][R_DIM];
  __shared__ float V_l[D_DIM][R_DIM];
  __shared__ float W_l[D_DIM][R_DIM];
  __shared__ float m_l[D_DIM];
  __shared__ float red[64];
  __shared__ float Linv_s[R_DIM][R_DIM];
  __shared__ float q_s[R_DIM];
  __shared__ float c0_s[1];
  __shared__ float redA[D_DIM], redB[D_DIM], redC[D_DIM];

  const float dl    = delta[k * D_DIM + d];
  const float s_inv = expf(-dl);
  const float mv    = m[k * D_DIM + d];
  m_l[d] = mv;
  const float* Up = U + (size_t)(k * D_DIM + d) * R_DIM;
#pragma unroll
  for (int r = 0; r < R_DIM; ++r) {
    float u = Up[r];
    U_l[d][r] = u;
    V_l[d][r] = u * s_inv;
  }
  redA[d] = dl;
  redB[d] = mv * mv * s_inv;
  redC[d] = (d < K_DIM) ? lar[d] : 0.f;
  __syncthreads();

  if (d < 64) {
    const int r = d >> 3, s = d & 7;
    float acc = (r == s) ? 1.0f : 0.0f;
#pragma unroll 8
    for (int dd = 0; dd < D_DIM; ++dd) acc += U_l[dd][r] * V_l[dd][s];
    red[d] = acc;
  }
  __syncthreads();

  for (int off = 64; off > 0; off >>= 1) {
    if (d < off) {
      redA[d] += redA[d + off];
      redB[d] += redB[d + off];
      redC[d] += redC[d + off];
    }
    __syncthreads();
  }

  if (d == 0) {
    float Lm[8][8];
#pragma unroll
    for (int i = 0; i < 8; ++i) {
#pragma unroll
      for (int j = 0; j < 8; ++j) {
        if (j > i) continue;
        float sum = red[i * 8 + j];
#pragma unroll
        for (int p = 0; p < 8; ++p)
          if (p < j) sum -= Lm[i][p] * Lm[j][p];
        if (i == j) Lm[i][i] = sqrtf(sum);
        else        Lm[i][j] = sum / Lm[j][j];
      }
    }
    float ld = 0.f;
#pragma unroll
    for (int i = 0; i < 8; ++i) ld += logf(Lm[i][i]);

    float Li[8][8];
#pragma unroll
    for (int i = 0; i < 8; ++i)
#pragma unroll
      for (int j = 0; j < 8; ++j) Li[i][j] = 0.f;
#pragma unroll
    for (int j = 0; j < 8; ++j) {
      Li[j][j] = 1.0f / Lm[j][j];
#pragma unroll
      for (int i = 0; i < 8; ++i) {
        if (i <= j) continue;
        float sum = 0.f;
#pragma unroll
        for (int p = 0; p < 8; ++p)
          if (p >= j && p < i) sum += Lm[i][p] * Li[p][j];
        Li[i][j] = -sum / Lm[i][i];
      }
    }
#pragma unroll
    for (int i = 0; i < 8; ++i)
#pragma unroll
      for (int j = 0; j < 8; ++j) Linv_s[i][j] = Li[i][j];

    const float mean = redC[0] * (1.0f / K_DIM);
    const float log_alpha = lar[k] - mean;       // /eps, eps=1
    const float logdetS = redA[0] + 2.0f * ld;
    const float LOG2PI = 1.8378770664093453f;
    const float log_norm = 0.5f * ((float)D_DIM * LOG2PI + logdetS);
    c0_s[0] = log_alpha - log_norm - 0.5f * redB[0];
  }
  __syncthreads();

  float Wr[R_DIM];
#pragma unroll
  for (int r = 0; r < R_DIM; ++r) {
    float acc = 0.f;
#pragma unroll
    for (int s2 = 0; s2 < R_DIM; ++s2)
      if (s2 <= r) acc += V_l[d][s2] * Linv_s[r][s2];
    Wr[r] = acc;
    W_l[d][r] = acc;
  }
  __syncthreads();

  if (d < R_DIM) {
    float acc = 0.f;
#pragma unroll 8
    for (int dd = 0; dd < D_DIM; ++dd) acc += W_l[dd][d] * m_l[dd];
    q_s[d] = acc;
  }
  __syncthreads();

  float hp = mv * s_inv;
#pragma unroll
  for (int r = 0; r < R_DIM; ++r) hp -= q_s[r] * Wr[r];

  const float INV_SQRT2 = 0.70710678118654752f;
  unsigned short* T = (unsigned short*)ws;
  const int kg = k >> 4, kl = k & 15;
  const int chunk = d >> 5, pos = d & 31;
  // idx(kg,ch,cc,kl,pos) = (((kg*8+ch)*9 + cc)*16 + kl)*32 + pos ; cc stride 512
  const size_t by = (((size_t)(kg * 8 + chunk) * 9) * 16 + kl) * 32 + pos;
  const size_t bq = (((size_t)(kg * 8 + chunk + 4) * 9) * 16 + kl) * 32 + pos;
#pragma unroll
  for (int cc = 0; cc < 8; ++cc) {
    T[by + (size_t)cc * 512] = f2bf(Wr[cc] * INV_SQRT2);
    T[bq + (size_t)cc * 512] = 0;
  }
  T[by + 8 * 512] = f2bf(hp);
  T[bq + 8 * 512] = f2bf(-0.5f * s_inv);

  if (d == 0) {
    float qq = 0.f;
#pragma unroll
    for (int r = 0; r < R_DIM; ++r) qq += q_s[r] * q_s[r];
    ws[WS_C0F + k] = c0_s[0] + 0.5f * qq;   // c0' = c0 + 0.5*||q||^2
  }
}

// ---------------------------------------------------------------------------
// Fused MFMA kernel: block = 512 thr = 8 waves = 32 rows x ALL 64 k.
// Waves: wr (2 row-waves) x wc (4 col-waves = kg). T double-buffered
// 2 x 36KB via global_load_lds; X converted in-block. 9 MFMA/iter (no pad
// col). Per-k sums in registers (B-lane owns one k); logits -> vals2 ->
// 64-lane butterfly logsumexp -> out. Grid = 256 blocks (1/CU, 99 KB LDS).
// ---------------------------------------------------------------------------
__global__ __launch_bounds__(512, 1) void logz_full(
    const float* __restrict__ y, const float* __restrict__ ws,
    float* __restrict__ out) {
  __shared__ __align__(16) char smem[16896 + 2 * 36864];  // sX | sT[2]
  __shared__ float vals2[32 * 66];                         // [row][k], stride 66

  unsigned short* sX = (unsigned short*)smem;              // 32 x XSTR
  unsigned short* sT = (unsigned short*)(smem + 16896);    // [2][4 kg][9 cc][16][32]

  const int tid   = threadIdx.x;            // 0..511
  const int lane  = tid & 63;
  const int wv    = tid >> 6;               // 0..7
  const int wr    = wv & 1;                 // row-wave
  const int wc    = wv >> 1;                // col-wave = kg
  const int col_l = lane & 15;
  const int quad  = lane >> 4;
  const int r0    = (int)blockIdx.x * 32;

  // ---- issue T chunk 0 into buf 0 (async): 36 x 1KB insts, waves strided ----
  for (int mm = wv; mm < 36; mm += 8) {
    const int kgm = mm / 9, seg = mm - kgm * 9;    // seg = cc
    const float* src = ws + (size_t)(kgm * 8 + 0) * 2304 + seg * 256 + lane * 4;
    __builtin_amdgcn_global_load_lds(
        (const __attribute__((address_space(1))) void*)src,
        (__attribute__((address_space(3))) void*)(sT + (kgm * 9 + seg) * 512),
        16, 0, 0);
  }

  // ---- convert X = [bf16(y), bf16(y^2)] into sX (overlaps T staging) ----
  {
#pragma unroll
    for (int j = 0; j < 2; ++j) {
      const int idx = tid + j * 512;        // granule 0..1023
      const int row = idx >> 5, g = idx & 31;
      const float4* ya = (const float4*)y + (size_t)(r0 + row) * 32 + (g & 15) * 2;
      float4 a = ya[0], b = ya[1];
      if (g >= 16) {
        a.x *= a.x; a.y *= a.y; a.z *= a.z; a.w *= a.w;
        b.x *= b.x; b.y *= b.y; b.z *= b.z; b.w *= b.w;
      }
      union { unsigned short us[8]; uint4 v; } o;
      o.us[0] = f2bf(a.x); o.us[1] = f2bf(a.y); o.us[2] = f2bf(a.z); o.us[3] = f2bf(a.w);
      o.us[4] = f2bf(b.x); o.us[5] = f2bf(b.y); o.us[6] = f2bf(b.z); o.us[7] = f2bf(b.w);
      *(uint4*)(sX + row * XSTR + g * 8) = o.v;
    }
  }

  f32x4 acc[9];
#pragma unroll
  for (int f = 0; f < 9; ++f) { acc[f][0] = 0.f; acc[f][1] = 0.f; acc[f][2] = 0.f; acc[f][3] = 0.f; }

  const int rowA = wr * 16 + col_l;         // A-fragment row (0..31)

  for (int c = 0; c < 8; ++c) {
    __syncthreads();   // drains vmcnt: chunk c staged; prev compute done
    if (c < 7) {
      const int nb = (c + 1) & 1;
      for (int mm = wv; mm < 36; mm += 8) {
        const int kgm = mm / 9, seg = mm - kgm * 9;
        const float* src = ws + (size_t)(kgm * 8 + c + 1) * 2304 + seg * 256 + lane * 4;
        __builtin_amdgcn_global_load_lds(
            (const __attribute__((address_space(1))) void*)src,
            (__attribute__((address_space(3))) void*)(sT + nb * 18432 + (kgm * 9 + seg) * 512),
            16, 0, 0);
      }
    }
    // compute chunk c from buf c&1
    const bf16x8 a = *(const bf16x8*)(sX + rowA * XSTR + c * 32 + quad * 8);
    const unsigned short* tb = sT + (c & 1) * 18432 + wc * 4608;
#pragma unroll
    for (int f = 0; f < 9; ++f) {
      const bf16x8 b = *(const bf16x8*)(tb + (f * 16 + col_l) * 32 + quad * 8);
      acc[f] = __builtin_amdgcn_mfma_f32_16x16x32_bf16(a, b, acc[f], 0, 0, 0);
    }
  }

  // ---- epilogue: per-k logits fully in registers ----
  // thread owns k = wc*16 + col_l, rows wr*16 + quad*4 + reg
  const float cv = ws[WS_C0F + wc * 16 + col_l];
#pragma unroll
  for (int reg = 0; reg < 4; ++reg) {
    float v = acc[8][reg];                  // linear + diag term
#pragma unroll
    for (int cc = 0; cc < 8; ++cc) v += acc[cc][reg] * acc[cc][reg];
    vals2[(wr * 16 + quad * 4 + reg) * 66 + wc * 16 + col_l] = cv + v;
  }
  __syncthreads();

  // per-row 64-k logsumexp: 4 rows per wave, lane = k, butterfly
#pragma unroll
  for (int rr = 0; rr < 4; ++rr) {
    const int row = wv * 4 + rr;
    const float val = vals2[row * 66 + lane];
    float mx = val;
#pragma unroll
    for (int off = 1; off < 64; off <<= 1)
      mx = fmaxf(mx, __shfl_xor(mx, off, 64));
    float ex = expf(val - mx);
#pragma unroll
    for (int off = 1; off < 64; off <<= 1)
      ex += __shfl_xor(ex, off, 64);
    if (lane == 0) out[r0 + row] = mx + logf(ex);
  }
}

extern "C" void kernel_launch(void* const* d_in, const int* in_sizes, int n_in,
                              void* d_out, int out_size, void* d_ws, size_t ws_size,
                              hipStream_t stream) {
  const float* y     = (const float*)d_in[0];
  const float* m     = (const float*)d_in[1];
  const float* delta = (const float*)d_in[2];
  const float* U     = (const float*)d_in[3];
  const float* lar   = (const float*)d_in[4];
  float* out = (float*)d_out;
  float* ws  = (float*)d_ws;

  precomp_kernel<<<K_DIM, 128, 0, stream>>>(m, delta, U, lar, ws);
  logz_full<<<B_DIM / 32, 512, 0, stream>>>(y, ws, out);
}

// Round 10
// 79.968 us; speedup vs baseline: 1.0606x; 1.0043x over previous
//
#include <hip/hip_runtime.h>
#include <math.h>

#define D_DIM 128
#define K_DIM 64
#define R_DIM 8
#define B_DIM 8192
#define XSTR  264        // ushort per staged X row (256 data + 8 pad)

// ws layout (float offsets):
//   T  : bf16 [4 kg][8 chunk][9 cc][16 kl][32 k] = 147456 ushort = 73728 floats
//   c0 : float [K] at 73728
#define WS_C0F   73728

typedef __bf16 bf16x8 __attribute__((ext_vector_type(8)));
typedef float  f32x4  __attribute__((ext_vector_type(4)));

static __device__ inline unsigned short f2bf(float f) {
  union { float f; unsigned int u; } v; v.f = f;
  unsigned int u = v.u;
  unsigned int lsb = (u >> 16) & 1;
  u += 0x7fffu + lsb;                 // round-to-nearest-even
  return (unsigned short)(u >> 16);
}

// ---------------------------------------------------------------------------
// Per-k precompute (r9 layout, unchanged). Grid = K blocks, 128 threads.
// T layout [kg][chunk][cc][kl][32k]: chunks 0..3 = y-part, 4..7 = y^2-part;
// cc 0..7 = W/sqrt2 (y-part; 0 in y^2-part), cc 8 = h' (y) / -0.5*s_inv (y^2).
// Per-(kg,chunk) region is 9 KB contiguous -> staging = 9 x 1KB per wave.
// ---------------------------------------------------------------------------
__global__ __launch_bounds__(128) void precomp_kernel(
    const float* __restrict__ m, const float* __restrict__ delta,
    const float* __restrict__ U, const float* __restrict__ lar,
    float* __restrict__ ws) {
  const int k = blockIdx.x;
  const int d = threadIdx.x;  // 0..127

  __shared__ float U_l[D_DIM][R_DIM];
  __shared__ float V_l[D_DIM][R_DIM];
  __shared__ float W_l[D_DIM][R_DIM];
  __shared__ float m_l[D_DIM];
  __shared__ float red[64];
  __shared__ float Linv_s[R_DIM][R_DIM];
  __shared__ float q_s[R_DIM];
  __shared__ float c0_s[1];
  __shared__ float redA[D_DIM], redB[D_DIM], redC[D_DIM];

  const float dl    = delta[k * D_DIM + d];
  const float s_inv = expf(-dl);
  const float mv    = m[k * D_DIM + d];
  m_l[d] = mv;
  const float* Up = U + (size_t)(k * D_DIM + d) * R_DIM;
#pragma unroll
  for (int r = 0; r < R_DIM; ++r) {
    float u = Up[r];
    U_l[d][r] = u;
    V_l[d][r] = u * s_inv;
  }
  redA[d] = dl;
  redB[d] = mv * mv * s_inv;
  redC[d] = (d < K_DIM) ? lar[d] : 0.f;
  __syncthreads();

  if (d < 64) {
    const int r = d >> 3, s = d & 7;
    float acc = (r == s) ? 1.0f : 0.0f;
#pragma unroll 8
    for (int dd = 0; dd < D_DIM; ++dd) acc += U_l[dd][r] * V_l[dd][s];
    red[d] = acc;
  }
  __syncthreads();

  for (int off = 64; off > 0; off >>= 1) {
    if (d < off) {
      redA[d] += redA[d + off];
      redB[d] += redB[d + off];
      redC[d] += redC[d + off];
    }
    __syncthreads();
  }

  if (d == 0) {
    float Lm[8][8];
#pragma unroll
    for (int i = 0; i < 8; ++i) {
#pragma unroll
      for (int j = 0; j < 8; ++j) {
        if (j > i) continue;
        float sum = red[i * 8 + j];
#pragma unroll
        for (int p = 0; p < 8; ++p)
          if (p < j) sum -= Lm[i][p] * Lm[j][p];
        if (i == j) Lm[i][i] = sqrtf(sum);
        else        Lm[i][j] = sum / Lm[j][j];
      }
    }
    float ld = 0.f;
#pragma unroll
    for (int i = 0; i < 8; ++i) ld += logf(Lm[i][i]);

    float Li[8][8];
#pragma unroll
    for (int i = 0; i < 8; ++i)
#pragma unroll
      for (int j = 0; j < 8; ++j) Li[i][j] = 0.f;
#pragma unroll
    for (int j = 0; j < 8; ++j) {
      Li[j][j] = 1.0f / Lm[j][j];
#pragma unroll
      for (int i = 0; i < 8; ++i) {
        if (i <= j) continue;
        float sum = 0.f;
#pragma unroll
        for (int p = 0; p < 8; ++p)
          if (p >= j && p < i) sum += Lm[i][p] * Li[p][j];
        Li[i][j] = -sum / Lm[i][i];
      }
    }
#pragma unroll
    for (int i = 0; i < 8; ++i)
#pragma unroll
      for (int j = 0; j < 8; ++j) Linv_s[i][j] = Li[i][j];

    const float mean = redC[0] * (1.0f / K_DIM);
    const float log_alpha = lar[k] - mean;       // /eps, eps=1
    const float logdetS = redA[0] + 2.0f * ld;
    const float LOG2PI = 1.8378770664093453f;
    const float log_norm = 0.5f * ((float)D_DIM * LOG2PI + logdetS);
    c0_s[0] = log_alpha - log_norm - 0.5f * redB[0];
  }
  __syncthreads();

  float Wr[R_DIM];
#pragma unroll
  for (int r = 0; r < R_DIM; ++r) {
    float acc = 0.f;
#pragma unroll
    for (int s2 = 0; s2 < R_DIM; ++s2)
      if (s2 <= r) acc += V_l[d][s2] * Linv_s[r][s2];
    Wr[r] = acc;
    W_l[d][r] = acc;
  }
  __syncthreads();

  if (d < R_DIM) {
    float acc = 0.f;
#pragma unroll 8
    for (int dd = 0; dd < D_DIM; ++dd) acc += W_l[dd][d] * m_l[dd];
    q_s[d] = acc;
  }
  __syncthreads();

  float hp = mv * s_inv;
#pragma unroll
  for (int r = 0; r < R_DIM; ++r) hp -= q_s[r] * Wr[r];

  const float INV_SQRT2 = 0.70710678118654752f;
  unsigned short* T = (unsigned short*)ws;
  const int kg = k >> 4, kl = k & 15;
  const int chunk = d >> 5, pos = d & 31;
  const size_t by = (((size_t)(kg * 8 + chunk) * 9) * 16 + kl) * 32 + pos;
  const size_t bq = (((size_t)(kg * 8 + chunk + 4) * 9) * 16 + kl) * 32 + pos;
#pragma unroll
  for (int cc = 0; cc < 8; ++cc) {
    T[by + (size_t)cc * 512] = f2bf(Wr[cc] * INV_SQRT2);
    T[bq + (size_t)cc * 512] = 0;
  }
  T[by + 8 * 512] = f2bf(hp);
  T[bq + 8 * 512] = f2bf(-0.5f * s_inv);

  if (d == 0) {
    float qq = 0.f;
#pragma unroll
    for (int r = 0; r < R_DIM; ++r) qq += q_s[r] * q_s[r];
    ws[WS_C0F + k] = c0_s[0] + 0.5f * qq;   // c0' = c0 + 0.5*||q||^2
  }
}

// ---------------------------------------------------------------------------
// Fused MFMA kernel, multi-residency version: block = 256 thr = 4 waves =
// 16 rows x ALL 64 k (wave = one kg). Single-buffered T chunk (36 KB);
// latency hiding comes from 2-3 co-resident blocks per CU (implicit
// inter-block overlap) instead of an explicit double buffer that the
// barrier vmcnt-drain defeated. LDS ~49 KB -> 3 blocks/CU.
// Grid = 512 blocks (2/CU avg).
// ---------------------------------------------------------------------------
__global__ __launch_bounds__(256, 3) void logz_full(
    const float* __restrict__ y, const float* __restrict__ ws,
    float* __restrict__ out) {
  __shared__ __align__(16) unsigned short sX[16 * XSTR];        // 8448 B
  __shared__ __align__(16) unsigned short sT[4 * 9 * 16 * 32];  // 36864 B
  __shared__ float vals2[16 * 66];                              // 4224 B

  const int tid   = threadIdx.x;            // 0..255
  const int lane  = tid & 63;
  const int wv    = tid >> 6;               // 0..3 = col-wave = kg
  const int col_l = lane & 15;
  const int quad  = lane >> 4;
  const int r0    = (int)blockIdx.x * 16;

  // ---- convert X = [bf16(y), bf16(y^2)] into sX: 512 granules, 2/thread ----
  {
#pragma unroll
    for (int j = 0; j < 2; ++j) {
      const int idx = tid + j * 256;        // granule 0..511
      const int row = idx >> 5, g = idx & 31;
      const float4* ya = (const float4*)y + (size_t)(r0 + row) * 32 + (g & 15) * 2;
      float4 a = ya[0], b = ya[1];
      if (g >= 16) {
        a.x *= a.x; a.y *= a.y; a.z *= a.z; a.w *= a.w;
        b.x *= b.x; b.y *= b.y; b.z *= b.z; b.w *= b.w;
      }
      union { unsigned short us[8]; uint4 v; } o;
      o.us[0] = f2bf(a.x); o.us[1] = f2bf(a.y); o.us[2] = f2bf(a.z); o.us[3] = f2bf(a.w);
      o.us[4] = f2bf(b.x); o.us[5] = f2bf(b.y); o.us[6] = f2bf(b.z); o.us[7] = f2bf(b.w);
      *(uint4*)(sX + row * XSTR + g * 8) = o.v;
    }
  }

  f32x4 acc[9];
#pragma unroll
  for (int f = 0; f < 9; ++f) { acc[f][0] = 0.f; acc[f][1] = 0.f; acc[f][2] = 0.f; acc[f][3] = 0.f; }

  for (int c = 0; c < 8; ++c) {
    __syncthreads();   // LDS buffer free (prev chunk's compute done; X writes done)
    // stage chunk c: wave wv stages its kg's 9 KB region = 9 x 1KB insts
    {
      const float* src = ws + (size_t)(wv * 8 + c) * 2304;
#pragma unroll
      for (int j = 0; j < 9; ++j) {
        __builtin_amdgcn_global_load_lds(
            (const __attribute__((address_space(1))) void*)(src + j * 256 + lane * 4),
            (__attribute__((address_space(3))) void*)(sT + wv * 4608 + j * 512),
            16, 0, 0);
      }
    }
    __syncthreads();   // staging complete (vmcnt drain)
    // compute chunk c
    const bf16x8 a = *(const bf16x8*)(sX + col_l * XSTR + c * 32 + quad * 8);
    const unsigned short* tb = sT + wv * 4608;
#pragma unroll
    for (int f = 0; f < 9; ++f) {
      const bf16x8 b = *(const bf16x8*)(tb + (f * 16 + col_l) * 32 + quad * 8);
      acc[f] = __builtin_amdgcn_mfma_f32_16x16x32_bf16(a, b, acc[f], 0, 0, 0);
    }
  }

  // ---- epilogue: per-k logits in registers ----
  // thread owns k = wv*16 + col_l, rows quad*4 + reg
  const float cv = ws[WS_C0F + wv * 16 + col_l];
#pragma unroll
  for (int reg = 0; reg < 4; ++reg) {
    float v = acc[8][reg];                  // linear + diag term
#pragma unroll
    for (int cc = 0; cc < 8; ++cc) v += acc[cc][reg] * acc[cc][reg];
    vals2[(quad * 4 + reg) * 66 + wv * 16 + col_l] = cv + v;
  }
  __syncthreads();

  // per-row 64-k logsumexp: wave wv handles rows wv*4..wv*4+3, lane = k
#pragma unroll
  for (int rr = 0; rr < 4; ++rr) {
    const int row = wv * 4 + rr;
    const float val = vals2[row * 66 + lane];
    float mx = val;
#pragma unroll
    for (int off = 1; off < 64; off <<= 1)
      mx = fmaxf(mx, __shfl_xor(mx, off, 64));
    float ex = expf(val - mx);
#pragma unroll
    for (int off = 1; off < 64; off <<= 1)
      ex += __shfl_xor(ex, off, 64);
    if (lane == 0) out[r0 + row] = mx + logf(ex);
  }
}

extern "C" void kernel_launch(void* const* d_in, const int* in_sizes, int n_in,
                              void* d_out, int out_size, void* d_ws, size_t ws_size,
                              hipStream_t stream) {
  const float* y     = (const float*)d_in[0];
  const float* m     = (const float*)d_in[1];
  const float* delta = (const float*)d_in[2];
  const float* U     = (const float*)d_in[3];
  const float* lar   = (const float*)d_in[4];
  float* out = (float*)d_out;
  float* ws  = (float*)d_ws;

  precomp_kernel<<<K_DIM, 128, 0, stream>>>(m, delta, U, lar, ws);
  logz_full<<<B_DIM / 16, 256, 0, stream>>>(y, ws, out);
}